// Round 1
// baseline (93059.735 us; speedup 1.0000x reference)
//
#include <hip/hip_runtime.h>
#include <cmath>

#define B_   64
#define S_   1024
#define T_   300
#define E_   512
#define H_   512
#define V_   5000
#define HKQ_ 256

__device__ __forceinline__ float sigf(float x) { return 1.0f / (1.0f + __expf(-x)); }

// ---------------- generic tiled transpose: dst[C][R] = src[R][C] ----------------
__global__ void transpose_f32(const float* __restrict__ src, float* __restrict__ dst, int R, int C)
{
    __shared__ float tile[32][33];
    int c = blockIdx.x * 32 + threadIdx.x;
    int r = blockIdx.y * 32 + threadIdx.y;
    if (r < R && c < C) tile[threadIdx.y][threadIdx.x] = src[(long)r * C + c];
    __syncthreads();
    int wr = blockIdx.x * 32 + threadIdx.y;   // output row (= src col)
    int wc = blockIdx.y * 32 + threadIdx.x;   // output col (= src row)
    if (wr < C && wc < R) dst[(long)wr * R + wc] = tile[threadIdx.x][threadIdx.y];
}

// ---------------- teacher-forcing inputs: xall[t][k][b] = emb[tok(b,t)][k] ----------------
__global__ void gather_x(const float* __restrict__ emb, const int* __restrict__ y,
                         float* __restrict__ xall)
{
    int t = blockIdx.y;
    int tid = threadIdx.x;              // 256
    int b = tid & 63;
    int k = blockIdx.x * 4 + (tid >> 6);
    int tok = (t == 0) ? 0 : y[b * T_ + (t - 1)];
    xall[((long)t * H_ + k) * 64 + b] = emb[(long)tok * H_ + k];
}

// ---------------- fp32 tiled GEMM: C[M][N] = A[M][K] @ B[K][N] + bias ----------------
// EPI 0: plain (+bias). EPI 1: relu(+bias). EPI 2: logits (+bias, row remap m=(t*64+b) -> out[b][t][:], N-tail guard)
template<int EPI>
__global__ __launch_bounds__(256)
void gemm_f32(const float* __restrict__ A, const float* __restrict__ Bm,
              const float* __restrict__ bias, float* __restrict__ C,
              int M, int N, int K)
{
    __shared__ float As[16][68];   // [kk][m]
    __shared__ float Bs[16][68];   // [kk][n]
    const int tid = threadIdx.x;
    const int m0 = blockIdx.y << 6, n0 = blockIdx.x << 6;
    const int tx = tid & 15, ty = tid >> 4;
    const int arow = tid >> 2, ak = (tid & 3) << 2;
    const int brow = tid >> 4, bn = (tid & 15) << 2;
    const bool tail = (n0 + 64 > N);
    float acc[4][4] = {};
    for (int k0 = 0; k0 < K; k0 += 16) {
        float4 av = *(const float4*)(A + (long)(m0 + arow) * K + (k0 + ak));
        As[ak + 0][arow] = av.x; As[ak + 1][arow] = av.y;
        As[ak + 2][arow] = av.z; As[ak + 3][arow] = av.w;
        float4 bv;
        if (!tail) {
            bv = *(const float4*)(Bm + (long)(k0 + brow) * N + (n0 + bn));
        } else {
            float tmp[4];
            #pragma unroll
            for (int j = 0; j < 4; ++j) {
                int n = n0 + bn + j;
                tmp[j] = (n < N) ? Bm[(long)(k0 + brow) * N + n] : 0.f;
            }
            bv = make_float4(tmp[0], tmp[1], tmp[2], tmp[3]);
        }
        *(float4*)&Bs[brow][bn] = bv;
        __syncthreads();
        #pragma unroll
        for (int kk = 0; kk < 16; ++kk) {
            float4 a4 = *(const float4*)&As[kk][ty << 2];
            float4 b4 = *(const float4*)&Bs[kk][tx << 2];
            float aa[4] = {a4.x, a4.y, a4.z, a4.w};
            float bb[4] = {b4.x, b4.y, b4.z, b4.w};
            #pragma unroll
            for (int i = 0; i < 4; ++i)
                #pragma unroll
                for (int j = 0; j < 4; ++j) acc[i][j] = fmaf(aa[i], bb[j], acc[i][j]);
        }
        __syncthreads();
    }
    #pragma unroll
    for (int i = 0; i < 4; ++i) {
        const int m = m0 + (ty << 2) + i;
        long rbase;
        if (EPI == 2) rbase = (long)((m & 63) * T_ + (m >> 6)) * N;  // out[b][t][:]
        else          rbase = (long)m * N;
        #pragma unroll
        for (int j = 0; j < 4; ++j) {
            const int n = n0 + (tx << 2) + j;
            if (EPI == 2 && n >= N) continue;
            float v = acc[i][j] + bias[n];
            if (EPI == 1) v = fmaxf(v, 0.f);
            C[rbase + n] = v;
        }
    }
}

// ---------------- one LSTM cell step for all 64 batch (lane=batch) ----------------
// NSEG segments of 512 inputs each; first (NSEG-1)*512 use Wih, last 512 use Whh.
// 256 blocks x 2 j-units each; 8 waves: (rowgrp 2) x (k-quarter 4); LDS partial reduce.
template<int NSEG>
__global__ __launch_bounds__(512)
void lstm_step(const float* __restrict__ Wih, const float* __restrict__ Whh,
               const float* __restrict__ bih, const float* __restrict__ bhh,
               const float* __restrict__ act0, const float* __restrict__ act1,
               const float* __restrict__ act2,
               float* __restrict__ cstate, float* __restrict__ hOut, float* __restrict__ hcOut)
{
    constexpr int KTOT = NSEG * 512;
    constexpr int IH   = (NSEG - 1) * 512;
    constexpr int CHUNK = KTOT / 4;
    __shared__ float part[4][8][64];
    __shared__ float gv[8][64];
    const int tid = threadIdx.x;
    const int b = tid & 63;
    const int wv = __builtin_amdgcn_readfirstlane(tid >> 6);
    const int rowgrp = wv & 1, kq = wv >> 1;
    const int j0 = blockIdx.x * 2;
    int grow[4];
    #pragma unroll
    for (int ri = 0; ri < 4; ++ri) {
        int rr = rowgrp * 4 + ri;                 // rr = gate*2 + jj
        grow[ri] = ((rr >> 1) << 9) + j0 + (rr & 1);
    }
    const float* acts[3] = {act0, act1, act2};
    float acc[4] = {0.f, 0.f, 0.f, 0.f};
    const int klo = kq * CHUNK, khi = klo + CHUNK;
    for (int seg = klo >> 9; seg < ((khi + 511) >> 9); ++seg) {
        const float* ap = acts[seg];
        const int lo = (klo > (seg << 9)) ? klo : (seg << 9);
        const int hi = (khi < ((seg + 1) << 9)) ? khi : ((seg + 1) << 9);
        const bool useIH = ((seg << 9) < IH);
        const float* wb = useIH ? Wih : Whh;
        const int ldw = useIH ? IH : 512;
        const int off = useIH ? 0 : IH;
        const float* aB = ap - (long)(seg << 9) * 64;   // virtual base so index is k directly
        for (int k = lo; k < hi; ++k) {
            float a = aB[(long)k * 64 + b];
            #pragma unroll
            for (int ri = 0; ri < 4; ++ri)
                acc[ri] = fmaf(wb[(long)grow[ri] * ldw + (k - off)], a, acc[ri]);
        }
    }
    #pragma unroll
    for (int ri = 0; ri < 4; ++ri) part[kq][rowgrp * 4 + ri][b] = acc[ri];
    __syncthreads();
    {
        const int rr = tid >> 6;                  // 0..7
        const int g = ((rr >> 1) << 9) + j0 + (rr & 1);
        gv[rr][b] = part[0][rr][b] + part[1][rr][b] + part[2][rr][b] + part[3][rr][b]
                  + bih[g] + bhh[g];
    }
    __syncthreads();
    if (tid < 128) {
        const int jj = tid >> 6;
        const int j = j0 + jj;
        const float gi = gv[0 + jj][b], gf = gv[2 + jj][b];
        const float gg = gv[4 + jj][b], go = gv[6 + jj][b];
        const float cold = cstate[j * 64 + b];
        const float cn = sigf(gf) * cold + sigf(gi) * tanhf(gg);
        const float hn = sigf(go) * tanhf(cn);
        cstate[j * 64 + b] = cn;
        hOut[j * 64 + b] = hn;
        if (hcOut) hcOut[b * 1024 + j] = hn;      // h2 half of classifier input
    }
}

// ---------------- per-step attention, one block per batch element ----------------
__global__ __launch_bounds__(512)
void attn_step(const float* __restrict__ Wq, const float* __restrict__ bq,
               const float* __restrict__ kmat, const float* __restrict__ vmat,
               const float* __restrict__ h2cur, float* __restrict__ ctxOut,
               float* __restrict__ hcOut)
{
    __shared__ float h2L[512];
    __shared__ float qL[256];
    __shared__ float sL[1024];
    __shared__ float red[16];
    const int tid = threadIdx.x;
    const int b = blockIdx.x;
    h2L[tid] = h2cur[tid * 64 + b];
    __syncthreads();
    if (tid < 256) {
        const float* w = Wq + tid * 512;
        float a = bq[tid];
        for (int j = 0; j < 512; ++j) a = fmaf(w[j], h2L[j], a);
        qL[tid] = a;
    }
    __syncthreads();
    const int wv = tid >> 6, lane = tid & 63;
    const float* kb = kmat + ((long)b << 10) * HKQ_;
    for (int s = wv * 128; s < wv * 128 + 128; ++s) {
        const float* kr = kb + s * HKQ_;
        float p = 0.f;
        #pragma unroll
        for (int c = 0; c < 4; ++c) p = fmaf(kr[c * 64 + lane], qL[c * 64 + lane], p);
        #pragma unroll
        for (int off = 32; off > 0; off >>= 1) p += __shfl_xor(p, off, 64);
        if (lane == 0) sL[s] = p * 0.0625f;       // 1/sqrt(256)
    }
    __syncthreads();
    // softmax over s=0..1023
    float m = -1e30f;
    for (int i = tid; i < 1024; i += 512) m = fmaxf(m, sL[i]);
    #pragma unroll
    for (int off = 32; off > 0; off >>= 1) m = fmaxf(m, __shfl_xor(m, off, 64));
    if (lane == 0) red[wv] = m;
    __syncthreads();
    if (tid == 0) {
        float mm = red[0];
        #pragma unroll
        for (int i = 1; i < 8; ++i) mm = fmaxf(mm, red[i]);
        red[8] = mm;
    }
    __syncthreads();
    m = red[8];
    float ssum = 0.f;
    for (int i = tid; i < 1024; i += 512) { float p = __expf(sL[i] - m); sL[i] = p; ssum += p; }
    #pragma unroll
    for (int off = 32; off > 0; off >>= 1) ssum += __shfl_xor(ssum, off, 64);
    if (lane == 0) red[wv] = ssum;
    __syncthreads();
    if (tid == 0) {
        float ss = 0.f;
        #pragma unroll
        for (int i = 0; i < 8; ++i) ss += red[i];
        red[9] = 1.0f / ss;
    }
    __syncthreads();
    const float sinv = red[9];
    const int d = tid;                                  // 512 dims
    const float* vb = vmat + ((long)b << 10) * H_ + d;
    float accv = 0.f;
    for (int s = 0; s < 1024; s += 4) {
        const float4 w4 = *(const float4*)&sL[s];
        accv = fmaf(w4.x, vb[(long)(s + 0) * 512], accv);
        accv = fmaf(w4.y, vb[(long)(s + 1) * 512], accv);
        accv = fmaf(w4.z, vb[(long)(s + 2) * 512], accv);
        accv = fmaf(w4.w, vb[(long)(s + 3) * 512], accv);
    }
    const float cv = accv * sinv;
    ctxOut[d * 64 + b] = cv;
    hcOut[b * 1024 + 512 + d] = cv;                     // ctx half of classifier input
}

extern "C" void kernel_launch(void* const* d_in, const int* in_sizes, int n_in,
                              void* d_out, int out_size, void* d_ws, size_t ws_size,
                              hipStream_t stream)
{
    const float* enc  = (const float*)d_in[0];
    const int*   y    = (const int*)  d_in[1];
    const float* emb  = (const float*)d_in[2];
    const float* Wq   = (const float*)d_in[3];
    const float* bq   = (const float*)d_in[4];
    const float* Wk   = (const float*)d_in[5];
    const float* bk   = (const float*)d_in[6];
    const float* Wv   = (const float*)d_in[7];
    const float* bv   = (const float*)d_in[8];
    const float* Wih1 = (const float*)d_in[9];
    const float* bih1 = (const float*)d_in[10];
    const float* Whh1 = (const float*)d_in[11];
    const float* bhh1 = (const float*)d_in[12];
    const float* Wih2 = (const float*)d_in[13];
    const float* bih2 = (const float*)d_in[14];
    const float* Whh2 = (const float*)d_in[15];
    const float* bhh2 = (const float*)d_in[16];
    const float* Wcdn = (const float*)d_in[17];
    const float* bcdn = (const float*)d_in[18];
    const float* bcls = (const float*)d_in[19];
    float* out = (float*)d_out;
    float* ws  = (float*)d_ws;

    // workspace carve (fp32 elements), total ~374 MB
    size_t o = 0;
    float* k_nat = ws + o; o += (size_t)B_ * S_ * HKQ_;   // [B][S][256]
    float* v_nat = ws + o; o += (size_t)B_ * S_ * H_;     // [B][S][512]
    float* xall  = ws + o; o += (size_t)T_ * H_ * B_;     // [T][512][64]
    float* hc    = ws + o; o += (size_t)T_ * B_ * 1024;   // [T][B][h2|ctx]
    float* cdn   = ws + o; o += (size_t)T_ * B_ * H_;     // [T*B][512]
    float* Wkt   = ws + o; o += (size_t)E_ * HKQ_;
    float* Wvt   = ws + o; o += (size_t)E_ * H_;
    float* Wcdnt = ws + o; o += (size_t)1024 * H_;
    float* embT  = ws + o; o += (size_t)H_ * V_;
    float* h1T   = ws + o; o += 2 * 512 * 64;             // double-buffered [j][b]
    float* h2T   = ws + o; o += 2 * 512 * 64;
    float* ctxT  = ws + o; o += 2 * 512 * 64;
    float* c1    = ws + o; o += 512 * 64;
    float* c2    = ws + o; o += 512 * 64;

    // zero-init recurrent state (h1,h2,ctx double buffers + c1,c2 are contiguous)
    hipMemsetAsync(h1T, 0, (size_t)8 * 512 * 64 * sizeof(float), stream);

    dim3 tb32(32, 32);
    transpose_f32<<<dim3(16, 8),   tb32, 0, stream>>>(Wk,   Wkt,   256,  512);
    transpose_f32<<<dim3(16, 16),  tb32, 0, stream>>>(Wv,   Wvt,   512,  512);
    transpose_f32<<<dim3(32, 16),  tb32, 0, stream>>>(Wcdn, Wcdnt, 512,  1024);
    transpose_f32<<<dim3(16, 157), tb32, 0, stream>>>(emb,  embT,  5000, 512);

    gather_x<<<dim3(H_ / 4, T_), 256, 0, stream>>>(emb, y, xall);

    // k/v projections: one big GEMM each (M = B*S)
    gemm_f32<0><<<dim3(HKQ_ / 64, (B_ * S_) / 64), 256, 0, stream>>>(enc, Wkt, bk, k_nat, B_ * S_, HKQ_, E_);
    gemm_f32<0><<<dim3(H_   / 64, (B_ * S_) / 64), 256, 0, stream>>>(enc, Wvt, bv, v_nat, B_ * S_, H_,   E_);

    for (int t = 0; t < T_; ++t) {
        const int pp = t & 1, cc = pp ^ 1;
        lstm_step<3><<<256, 512, 0, stream>>>(Wih1, Whh1, bih1, bhh1,
            xall + (size_t)t * H_ * 64, ctxT + pp * 512 * 64, h1T + pp * 512 * 64,
            c1, h1T + cc * 512 * 64, nullptr);
        lstm_step<2><<<256, 512, 0, stream>>>(Wih2, Whh2, bih2, bhh2,
            h1T + cc * 512 * 64, h2T + pp * 512 * 64, nullptr,
            c2, h2T + cc * 512 * 64, hc + (size_t)t * B_ * 1024);
        attn_step<<<64, 512, 0, stream>>>(Wq, bq, k_nat, v_nat,
            h2T + cc * 512 * 64, ctxT + cc * 512 * 64, hc + (size_t)t * B_ * 1024);
    }

    // deferred classifier: cdn = relu(hc @ Wcdn^T + bcdn); out[b][t][:] = cdn @ emb^T + bcls
    gemm_f32<1><<<dim3(H_ / 64, (T_ * B_) / 64), 256, 0, stream>>>(hc,  Wcdnt, bcdn, cdn, T_ * B_, H_, 1024);
    gemm_f32<2><<<dim3((V_ + 63) / 64, (T_ * B_) / 64), 256, 0, stream>>>(cdn, embT, bcls, out, T_ * B_, V_, 512);
}